// Round 11
// baseline (876.047 us; speedup 1.0000x reference)
//
#include <hip/hip_runtime.h>

#define T_STEPS 1000
#define BATCH   256
#define NHID    200
#define ROWF    200      // floats per LDS row (800 B, 16B-aligned)
#define BETA_C  0.85f
#define THR_C   1.0f
#define SENT    (1ull << 50)

// WT2 row i (source neuron i) holds at float offset lo*4+k (lo<50,k<4):
// Wrec[(lo+50k)][i]. Lane lo reads ONE ds_read_b128 per firing source i,
// yielding the 4 weights for its outputs {lo, lo+50, lo+100, lo+150}.
//
// 4 waves per batch element: wave w gathers only source word w (~7 firing,
// one 8-wide sentinel-gated batch -> ONE lgkm wait), publishes per-lane
// float4 partials to LDS, then all waves reduce ((p0+p1)+p2)+p3, update all
// 200 neurons and ballot all 4 masks. Barriers are raw s_barrier with
// lgkmcnt-only drain: global spike stores stay fire-and-forget (no vmcnt
// drain on the critical path).

#define BARRIER_LGKM \
    asm volatile("s_waitcnt lgkmcnt(0)\n\ts_barrier" ::: "memory");

__launch_bounds__(256, 1)
__global__ void rsnn_kernel(const float* __restrict__ X,
                            const float* __restrict__ W1,
                            const float* __restrict__ b1,
                            const float* __restrict__ Wrec,
                            const float* __restrict__ brec,
                            const float* __restrict__ W2,
                            const float* __restrict__ b2,
                            float* __restrict__ out_cur2,
                            float* __restrict__ out_spk) {
#pragma clang fp contract(off)
    __shared__ float  WT2[NHID * ROWF];   // 160,000 B
    __shared__ float4 part[4][50];        //   3,200 B  -> 163,200 total

    const int tid = threadIdx.x;
    const int l   = tid & 63;            // lane
    const int w   = tid >> 6;            // wave id = source word id
    const int b   = blockIdx.x;

    // ---- stage Wrec (permuted transpose) into LDS ----
    for (int idx = tid; idx < NHID * NHID; idx += 256) {
        int r  = idx / NHID;             // Wrec row  (output neuron)
        int i  = idx - r * NHID;         // Wrec col  (source neuron)
        int lo = r % 50, k = r / 50;
        WT2[i * ROWF + lo * 4 + k] = Wrec[idx];
    }
    __syncthreads();   // once; full fence OK here

    const int lc = (l < 50) ? l : 49;    // lanes 50-63 duplicate lane 49
    float w1r[4][3], b1r[4], brr[4], w2r[4];
#pragma unroll
    for (int k = 0; k < 4; ++k) {
        int i = lc + 50 * k;
        w1r[k][0] = W1[i * 3 + 0];
        w1r[k][1] = W1[i * 3 + 1];
        w1r[k][2] = W1[i * 3 + 2];
        b1r[k] = b1[i];
        brr[k] = brec[i];
        w2r[k] = W2[i];
    }
    const float b2v = b2[0];

    float mem0 = 0.f, mem1 = 0.f, mem2 = 0.f, mem3 = 0.f;
    unsigned long long bm0 = 0, bm1 = 0, bm2 = 0, bm3 = 0;

    const float* xp = X + (size_t)b * 3;
    float x0 = xp[0], x1 = xp[1], x2 = xp[2];

    const float* ldsrow = WT2 + (size_t)lc * 4;
    const int    wbase  = 50 * w;

// one 8-wide slot: sentinel keeps ctz defined; clamp keeps the (0-gated)
// dummy load in-bounds; fma with gate in {0,1} is bit-exact.
#define GSLOT(K)                                                       \
    unsigned long long mm##K = m | SENT;                               \
    int   r##K = __builtin_ctzll(mm##K);                               \
    int   i##K = r##K > 49 ? 49 : r##K;                                \
    float g##K = (m != 0ull) ? 1.f : 0.f;                              \
    m &= m - 1;                                                        \
    const float4 gv##K = *(const float4*)(ldsrow + (i##K + wbase) * ROWF);

#define GACC(K)                                                        \
    pr0 = fmaf(g##K, gv##K.x, pr0);                                    \
    pr1 = fmaf(g##K, gv##K.y, pr1);                                    \
    pr2 = fmaf(g##K, gv##K.z, pr2);                                    \
    pr3 = fmaf(g##K, gv##K.w, pr3);

    for (int t = 0; t < T_STEPS; ++t) {
        // prefetch next step's input (used one iteration later)
        int   tn  = (t + 1 < T_STEPS) ? t + 1 : t;
        float nx0 = xp[(size_t)tn * BATCH * 3 + 0];
        float nx1 = xp[(size_t)tn * BATCH * 3 + 1];
        float nx2 = xp[(size_t)tn * BATCH * 3 + 2];

        // ---- A: gather this wave's source word (8-wide batch, 1 wait) ----
        unsigned long long m = (w == 0) ? bm0 : (w == 1) ? bm1 : (w == 2) ? bm2 : bm3;
        float pr0 = 0.f, pr1 = 0.f, pr2 = 0.f, pr3 = 0.f;
        while (m) {
            GSLOT(0) GSLOT(1) GSLOT(2) GSLOT(3)
            GSLOT(4) GSLOT(5) GSLOT(6) GSLOT(7)
            GACC(0) GACC(1) GACC(2) GACC(3)
            GACC(4) GACC(5) GACC(6) GACC(7)
        }

        // ---- B: publish per-lane word-partial (16 B/lane) ----
        if (l < 50) part[w][l] = float4{pr0, pr1, pr2, pr3};
        BARRIER_LGKM

        // ---- C: every wave reduces all 4 word-partials (word-blocked order) ----
        const float4 p0 = part[0][lc];
        const float4 p1 = part[1][lc];
        const float4 p2 = part[2][lc];
        const float4 p3 = part[3][lc];
        float rec0 = ((p0.x + p1.x) + p2.x) + p3.x;
        float rec1 = ((p0.y + p1.y) + p2.y) + p3.y;
        float rec2 = ((p0.z + p1.z) + p2.z) + p3.z;
        float rec3 = ((p0.w + p1.w) + p2.w) + p3.w;
        BARRIER_LGKM   // partials consumed; safe to overwrite next step

        // ---- D: membrane update (numpy op/rounding order preserved) ----
        float c0 = fmaf(x2, w1r[0][2], fmaf(x1, w1r[0][1], x0 * w1r[0][0])) + b1r[0];
        float c1 = fmaf(x2, w1r[1][2], fmaf(x1, w1r[1][1], x0 * w1r[1][0])) + b1r[1];
        float c2 = fmaf(x2, w1r[2][2], fmaf(x1, w1r[2][1], x0 * w1r[2][0])) + b1r[2];
        float c3 = fmaf(x2, w1r[3][2], fmaf(x1, w1r[3][1], x0 * w1r[3][0])) + b1r[3];

        float ba0 = ((BETA_C * mem0 + c0) + rec0) + brr[0];
        float ba1 = ((BETA_C * mem1 + c1) + rec1) + brr[1];
        float ba2 = ((BETA_C * mem2 + c2) + rec2) + brr[2];
        float ba3 = ((BETA_C * mem3 + c3) + rec3) + brr[3];

        float nm0 = (mem0 > THR_C) ? 0.f : ba0;
        float nm1 = (mem1 > THR_C) ? 0.f : ba1;
        float nm2 = (mem2 > THR_C) ? 0.f : ba2;
        float nm3 = (mem3 > THR_C) ? 0.f : ba3;

        float sp0 = (nm0 > THR_C) ? 1.f : 0.f;
        float sp1 = (nm1 > THR_C) ? 1.f : 0.f;
        float sp2 = (nm2 > THR_C) ? 1.f : 0.f;
        float sp3 = (nm3 > THR_C) ? 1.f : 0.f;

        mem0 = nm0; mem1 = nm1; mem2 = nm2; mem3 = nm3;

        // ---- E: outputs. wave w stores its 50-spike slice; wave 0 does cur2 ----
        if (l < 50) {
            float spw = (w == 0) ? sp0 : (w == 1) ? sp1 : (w == 2) ? sp2 : sp3;
            out_spk[(size_t)t * BATCH * NHID + (size_t)b * NHID + wbase + l] = spw;
        }
        if (w == 0) {
            // cur2 = sum_j sp_j * W2_j  (terminal output: tree order OK)
            float v = (l < 50)
                ? fmaf(sp3, w2r[3], fmaf(sp2, w2r[2], fmaf(sp1, w2r[1], sp0 * w2r[0])))
                : 0.f;
            for (int o = 32; o >= 1; o >>= 1) v += __shfl_xor(v, o);
            if (l == 0) out_cur2[(size_t)t * BATCH + b] = v + b2v;
        }

        // ---- F: ballots (every wave computes all 4 masks identically) ----
        bm0 = __ballot((l < 50) && (sp0 > 0.5f));
        bm1 = __ballot((l < 50) && (sp1 > 0.5f));
        bm2 = __ballot((l < 50) && (sp2 > 0.5f));
        bm3 = __ballot((l < 50) && (sp3 > 0.5f));

        x0 = nx0; x1 = nx1; x2 = nx2;
    }
#undef GSLOT
#undef GACC
}

extern "C" void kernel_launch(void* const* d_in, const int* in_sizes, int n_in,
                              void* d_out, int out_size, void* d_ws, size_t ws_size,
                              hipStream_t stream) {
    const float* X    = (const float*)d_in[0];
    const float* W1   = (const float*)d_in[1];
    const float* b1   = (const float*)d_in[2];
    const float* Wrec = (const float*)d_in[3];
    const float* brec = (const float*)d_in[4];
    const float* W2   = (const float*)d_in[5];
    const float* b2   = (const float*)d_in[6];

    float* out_cur2 = (float*)d_out;                            // [T,B,1] flat
    float* out_spk  = (float*)d_out + (size_t)T_STEPS * BATCH;  // [T,B,200] flat

    rsnn_kernel<<<BATCH, 256, 0, stream>>>(X, W1, b1, Wrec, brec, W2, b2,
                                           out_cur2, out_spk);
}